// Round 2
// baseline (387.517 us; speedup 1.0000x reference)
//
#include <hip/hip_runtime.h>
#include <hip/hip_cooperative_groups.h>

namespace cg = cooperative_groups;

#define NN 16384
#define DIM 64
#define CBLK 256          // cooperative blocks (1 per CU)
#define RPB (NN / CBLK)   // 64 rows owned per block

// ---- pos/neg: rowwise sums of relu(g) and relu(-g). One block per row. ----
__global__ __launch_bounds__(256) void rowsum_kernel(const float* __restrict__ g,
                                                     float* __restrict__ pos,
                                                     float* __restrict__ neg) {
    int row = blockIdx.x;
    const float4* grow = reinterpret_cast<const float4*>(g + (size_t)row * NN);
    float p = 0.f, n = 0.f;
    #pragma unroll 4
    for (int i = threadIdx.x; i < NN / 4; i += 256) {
        float4 v = grow[i];
        p += fmaxf(v.x, 0.f) + fmaxf(v.y, 0.f) + fmaxf(v.z, 0.f) + fmaxf(v.w, 0.f);
        n += fmaxf(-v.x, 0.f) + fmaxf(-v.y, 0.f) + fmaxf(-v.z, 0.f) + fmaxf(-v.w, 0.f);
    }
    #pragma unroll
    for (int o = 32; o > 0; o >>= 1) {
        p += __shfl_down(p, o, 64);
        n += __shfl_down(n, o, 64);
    }
    __shared__ float sp[4], sn[4];
    int wid = threadIdx.x >> 6;
    if ((threadIdx.x & 63) == 0) { sp[wid] = p; sn[wid] = n; }
    __syncthreads();
    if (threadIdx.x == 0) {
        pos[row] = sp[0] + sp[1] + sp[2] + sp[3];
        neg[row] = sn[0] + sn[1] + sn[2] + sn[3];
    }
}

// ---- everything else, fused: init + 3x(reduce,update) + final head ----
__global__ __launch_bounds__(256, 1) void coop_kernel(
    const int* __restrict__ s_mask, const int* __restrict__ vptr,
    const float* __restrict__ w1, const float* __restrict__ W2,
    const float* __restrict__ W3, const float* __restrict__ w4,
    const float* __restrict__ w5, const float* __restrict__ W6,
    const float* __restrict__ W7, const float* __restrict__ pos,
    const float* __restrict__ neg, float* __restrict__ partials,
    float* __restrict__ out)
{
    cg::grid_group grid = cg::this_grid();

    __shared__ float uown[RPB][DIM];   // this block's 64 u-rows, resident all kernel
    __shared__ float ss[DIM];
    __shared__ float a3s[DIM], b3s[DIM], w1s[DIM];
    __shared__ float posr[RPB], negr[RPB], xr[RPB];
    __shared__ float ps[4][DIM];
    __shared__ float hred[128];

    const int tid = threadIdx.x;
    const int b = blockIdx.x;
    const int sub = tid >> 6;   // wave id; wave w owns rows r with r%4==w
    const int d = tid & 63;
    const int row0 = b * RPB;

    // lane-private W2 row: w2r[k] = W2[d][k]  (static indices -> stays in VGPRs)
    float w2r[DIM];
    #pragma unroll
    for (int k = 0; k < DIM; k += 4) {
        const float4 t = *reinterpret_cast<const float4*>(&W2[d * DIM + k]);
        w2r[k] = t.x; w2r[k + 1] = t.y; w2r[k + 2] = t.z; w2r[k + 3] = t.w;
    }

    // a3 = W3 @ relu(w4), b3 = W3 @ relu(-w4)  (redundant per block, trivial)
    if (tid < DIM) {
        float a = 0.f, bb = 0.f;
        #pragma unroll
        for (int k = 0; k < DIM; ++k) {
            const float w = W3[tid * DIM + k];
            a  += w * fmaxf(w4[k], 0.f);
            bb += w * fmaxf(-w4[k], 0.f);
        }
        a3s[tid] = a; b3s[tid] = bb; w1s[tid] = w1[tid];
    }
    for (int r = tid; r < RPB; r += 256) {
        posr[r] = pos[row0 + r];
        negr[r] = neg[row0 + r];
        xr[r]   = (float)s_mask[row0 + r];
    }
    __syncthreads();

    // u1 = relu(base); write partials slot 0
    {
        float pacc = 0.f;
        for (int r = sub; r < RPB; r += 4) {
            const float base = xr[r] * w1s[d] + posr[r] * a3s[d] + negr[r] * b3s[d];
            const float uu = fmaxf(base, 0.f);
            uown[r][d] = uu;
            pacc += uu;
        }
        ps[sub][d] = pacc;
        __syncthreads();
        if (sub == 0) partials[b * DIM + d] = ps[0][d] + ps[1][d] + ps[2][d] + ps[3][d];
    }

    for (int t = 0; t < 3; ++t) {
        grid.sync();
        // ss = sum over blocks of partials[slot t] (deterministic, every block redundantly)
        {
            const float* pslot = partials + (size_t)t * CBLK * DIM;
            float acc = 0.f;
            for (int p = sub; p < CBLK; p += 4) acc += pslot[p * DIM + d];
            ps[sub][d] = acc;                    // grid.sync's block barrier protects reuse
            __syncthreads();
            if (sub == 0) ss[d] = ps[0][d] + ps[1][d] + ps[2][d] + ps[3][d];
            __syncthreads();
        }
        // c2[d] = summ @ W2^T  (hoisted out of the row loop)
        float c2 = 0.f;
        #pragma unroll
        for (int k = 0; k < DIM; k += 4) {
            const float4 s4 = *reinterpret_cast<const float4*>(&ss[k]);
            c2 += w2r[k] * s4.x + w2r[k + 1] * s4.y + w2r[k + 2] * s4.z + w2r[k + 3] * s4.w;
        }
        // u[r] = relu(base + c2 - u[r]@W2^T); rows private to this wave -> no barrier
        float pacc = 0.f;
        for (int r = sub; r < RPB; r += 4) {
            float acc = 0.f;
            #pragma unroll
            for (int k = 0; k < DIM; k += 4) {
                const float4 u4 = *reinterpret_cast<const float4*>(&uown[r][k]);
                acc += w2r[k] * u4.x + w2r[k + 1] * u4.y + w2r[k + 2] * u4.z + w2r[k + 3] * u4.w;
            }
            const float base = xr[r] * w1s[d] + posr[r] * a3s[d] + negr[r] * b3s[d];
            const float uu = fmaxf(base + c2 - acc, 0.f);
            uown[r][d] = uu;   // wave-lockstep: all reads of row r precede this write
            pacc += uu;
        }
        ps[sub][d] = pacc;
        __syncthreads();
        if (sub == 0) partials[(size_t)(t + 1) * CBLK * DIM + b * DIM + d] =
            ps[0][d] + ps[1][d] + ps[2][d] + ps[3][d];
    }

    // final: summ4, then q(v) computed by the block owning row v
    grid.sync();
    {
        const float* pslot = partials + (size_t)3 * CBLK * DIM;
        float acc = 0.f;
        for (int p = sub; p < CBLK; p += 4) acc += pslot[p * DIM + d];
        ps[sub][d] = acc;
        __syncthreads();
        if (sub == 0) ss[d] = ps[0][d] + ps[1][d] + ps[2][d] + ps[3][d];
        __syncthreads();
    }
    const int v = *vptr;
    if (b == (v >> 6)) {                  // RPB == 64
        const int vr = v & (RPB - 1);
        if (tid < 128) {
            float h = 0.f;
            if (tid < 64) {
                #pragma unroll
                for (int k = 0; k < DIM; ++k) h += W6[tid * DIM + k] * ss[k];
            } else {
                const int dd = tid - 64;
                #pragma unroll
                for (int k = 0; k < DIM; ++k) h += W7[dd * DIM + k] * uown[vr][k];
            }
            hred[tid] = fmaxf(h, 0.f) * w5[tid];
        }
        __syncthreads();
        if (tid == 0) {
            float s = 0.f;
            for (int i = 0; i < 128; ++i) s += hred[i];
            out[0] = s;
        }
    }
}

extern "C" void kernel_launch(void* const* d_in, const int* in_sizes, int n_in,
                              void* d_out, int out_size, void* d_ws, size_t ws_size,
                              hipStream_t stream) {
    const float* graph  = (const float*)d_in[0];
    const int*   s_mask = (const int*)d_in[1];
    const int*   vptr   = (const int*)d_in[2];
    const float* w1     = (const float*)d_in[3];
    const float* W2     = (const float*)d_in[4];
    const float* W3     = (const float*)d_in[5];
    const float* w4     = (const float*)d_in[6];
    const float* w5     = (const float*)d_in[7];
    const float* W6     = (const float*)d_in[8];
    const float* W7     = (const float*)d_in[9];
    float* out = (float*)d_out;

    float* ws       = (float*)d_ws;
    float* pos      = ws;                 // NN
    float* neg      = pos + NN;           // NN
    float* partials = neg + NN;           // 4 slots * CBLK * DIM = 64K floats
    // total ws use: (2*16384 + 65536) * 4 B = 384 KB

    rowsum_kernel<<<NN, 256, 0, stream>>>(graph, pos, neg);

    void* args[] = { (void*)&s_mask, (void*)&vptr, (void*)&w1, (void*)&W2,
                     (void*)&W3, (void*)&w4, (void*)&w5, (void*)&W6, (void*)&W7,
                     (void*)&pos, (void*)&neg, (void*)&partials, (void*)&out };
    hipLaunchCooperativeKernel((const void*)coop_kernel, dim3(CBLK), dim3(256),
                               args, 0, stream);
}

// Round 3
// 374.301 us; speedup vs baseline: 1.0353x; 1.0353x over previous
//
#include <hip/hip_runtime.h>

#define NN 16384
#define DIM 64
#define RSBLK 2048              // rowsum blocks: 8 per CU, all co-resident
#define ROWS_PER_BLK 8          // NN / RSBLK
#define UPDBLK 256              // update blocks: 1 per CU
#define RPB_U (NN / UPDBLK)     // 64 rows per update block
#define SLOT (RSBLK * DIM)      // floats per partials slot (slot0 uses all 2048 entries)

// ---- fused: rowwise relu-sums of graph + u1 = relu(base) + partials slot 0 ----
// One WAVE per row: 64 lanes x float4 = 1KB per load instr, butterfly reduce in-wave.
__global__ __launch_bounds__(256, 8) void rowsum_init_kernel(
    const float* __restrict__ g, const int* __restrict__ s_mask,
    const float* __restrict__ W3, const float* __restrict__ w4,
    const float* __restrict__ w1,
    float* __restrict__ pos, float* __restrict__ neg,
    float* __restrict__ u, float* __restrict__ partials)
{
    __shared__ float a3s[DIM], b3s[DIM], w1s[DIM];
    __shared__ float ps[4][DIM];
    const int tid  = threadIdx.x;
    const int wid  = tid >> 6;
    const int lane = tid & 63;
    const int row0 = blockIdx.x * ROWS_PER_BLK;

    if (tid < DIM) {  // a3 = W3@relu(w4), b3 = W3@relu(-w4) (redundant per block, L2-hot)
        float a = 0.f, bb = 0.f;
        for (int k = 0; k < DIM; ++k) {
            const float w = W3[tid * DIM + k];
            a  += w * fmaxf(w4[k], 0.f);
            bb += w * fmaxf(-w4[k], 0.f);
        }
        a3s[tid] = a; b3s[tid] = bb; w1s[tid] = w1[tid];
    }
    __syncthreads();

    float uacc = 0.f;
    #pragma unroll
    for (int rr = 0; rr < 2; ++rr) {
        const int row = row0 + wid * 2 + rr;
        const float4* grow = reinterpret_cast<const float4*>(g + (size_t)row * NN);
        float p = 0.f, n = 0.f;
        #pragma unroll 4
        for (int i = lane; i < NN / 4; i += 64) {
            const float4 v = grow[i];
            p += fmaxf(v.x, 0.f) + fmaxf(v.y, 0.f) + fmaxf(v.z, 0.f) + fmaxf(v.w, 0.f);
            n += fmaxf(-v.x, 0.f) + fmaxf(-v.y, 0.f) + fmaxf(-v.z, 0.f) + fmaxf(-v.w, 0.f);
        }
        #pragma unroll
        for (int o = 1; o < 64; o <<= 1) {  // butterfly: all lanes get the row sums
            p += __shfl_xor(p, o, 64);
            n += __shfl_xor(n, o, 64);
        }
        const float x  = (float)s_mask[row];
        const float uu = fmaxf(x * w1s[lane] + p * a3s[lane] + n * b3s[lane], 0.f);
        u[(size_t)row * DIM + lane] = uu;
        uacc += uu;
        if (lane == 0) { pos[row] = p; neg[row] = n; }
    }
    ps[wid][lane] = uacc;
    __syncthreads();
    if (tid < DIM)
        partials[blockIdx.x * DIM + tid] = ps[0][tid] + ps[1][tid] + ps[2][tid] + ps[3][tid];
}

// ---- one message-passing iteration: redundant summ-reduce + row update ----
__global__ __launch_bounds__(256) void upd_kernel(
    const int* __restrict__ s_mask, const float* __restrict__ w1,
    const float* __restrict__ W2, const float* __restrict__ W3,
    const float* __restrict__ w4,
    const float* __restrict__ pos, const float* __restrict__ neg,
    float* __restrict__ u, float* __restrict__ partials,
    int slot_in, int Pcount)
{
    __shared__ float a3s[DIM], b3s[DIM], w1s[DIM], ss[DIM];
    __shared__ float posr[RPB_U], negr[RPB_U], xr[RPB_U];
    __shared__ float4 ps4[16][16];
    __shared__ float ps[4][DIM];
    const int tid  = threadIdx.x;
    const int row0 = blockIdx.x * RPB_U;

    if (tid < 64) {
        float a = 0.f, bb = 0.f;
        for (int k = 0; k < DIM; ++k) {
            const float w = W3[tid * DIM + k];
            a  += w * fmaxf(w4[k], 0.f);
            bb += w * fmaxf(-w4[k], 0.f);
        }
        a3s[tid] = a; b3s[tid] = bb; w1s[tid] = w1[tid];
    } else if (tid < 128) {
        posr[tid - 64] = pos[row0 + tid - 64];
    } else if (tid < 192) {
        negr[tid - 128] = neg[row0 + tid - 128];
    } else {
        xr[tid - 192] = (float)s_mask[row0 + tid - 192];
    }

    // ss[d] = sum over partials slot_in (every block redundantly; L2-resident)
    {
        const int d4 = tid & 15, s16 = tid >> 4;
        const float4* pin = reinterpret_cast<const float4*>(partials + (size_t)slot_in * SLOT);
        float4 a4 = {0.f, 0.f, 0.f, 0.f};
        for (int p = s16; p < Pcount; p += 16) {
            const float4 t4 = pin[p * 16 + d4];
            a4.x += t4.x; a4.y += t4.y; a4.z += t4.z; a4.w += t4.w;
        }
        ps4[s16][d4] = a4;
        __syncthreads();
        if (tid < 16) {
            float4 r = ps4[0][tid];
            #pragma unroll
            for (int s = 1; s < 16; ++s) {
                const float4 t4 = ps4[s][tid];
                r.x += t4.x; r.y += t4.y; r.z += t4.z; r.w += t4.w;
            }
            reinterpret_cast<float4*>(ss)[tid] = r;
        }
        __syncthreads();
    }

    const int d = tid & 63, sub = tid >> 6;
    float w2r[DIM];  // lane-private W2 row (static idx -> VGPRs)
    #pragma unroll
    for (int k = 0; k < DIM; k += 4) {
        const float4 t = *reinterpret_cast<const float4*>(&W2[d * DIM + k]);
        w2r[k] = t.x; w2r[k + 1] = t.y; w2r[k + 2] = t.z; w2r[k + 3] = t.w;
    }
    float c2 = 0.f;  // summ @ W2^T, hoisted
    #pragma unroll
    for (int k = 0; k < DIM; ++k) c2 += w2r[k] * ss[k];

    float uacc = 0.f;
    for (int r = sub; r < RPB_U; r += 4) {
        const int row = row0 + r;
        const float4* ur = reinterpret_cast<const float4*>(u + (size_t)row * DIM);
        float aA = 0.f, aB = 0.f, aC = 0.f, aD = 0.f;  // 4 independent FMA chains
        #pragma unroll
        for (int k4 = 0; k4 < 16; k4 += 4) {
            const float4 x0 = ur[k4 + 0];
            aA += w2r[(k4+0)*4+0]*x0.x + w2r[(k4+0)*4+1]*x0.y + w2r[(k4+0)*4+2]*x0.z + w2r[(k4+0)*4+3]*x0.w;
            const float4 x1 = ur[k4 + 1];
            aB += w2r[(k4+1)*4+0]*x1.x + w2r[(k4+1)*4+1]*x1.y + w2r[(k4+1)*4+2]*x1.z + w2r[(k4+1)*4+3]*x1.w;
            const float4 x2 = ur[k4 + 2];
            aC += w2r[(k4+2)*4+0]*x2.x + w2r[(k4+2)*4+1]*x2.y + w2r[(k4+2)*4+2]*x2.z + w2r[(k4+2)*4+3]*x2.w;
            const float4 x3 = ur[k4 + 3];
            aD += w2r[(k4+3)*4+0]*x3.x + w2r[(k4+3)*4+1]*x3.y + w2r[(k4+3)*4+2]*x3.z + w2r[(k4+3)*4+3]*x3.w;
        }
        const float acc = (aA + aB) + (aC + aD);
        const float uu = fmaxf(xr[r] * w1s[d] + posr[r] * a3s[d] + negr[r] * b3s[d] + c2 - acc, 0.f);
        u[(size_t)row * DIM + d] = uu;   // row read fully above; only this wave touches it
        uacc += uu;
    }
    ps[sub][d] = uacc;
    __syncthreads();
    if (tid < DIM)
        partials[(size_t)(slot_in + 1) * SLOT + blockIdx.x * DIM + tid] =
            ps[0][tid] + ps[1][tid] + ps[2][tid] + ps[3][tid];
}

// ---- q(v): reduce last partials slot -> summ; h6=summ@W6^T, h7=u[v]@W7^T ----
__global__ void final_kernel(const float* __restrict__ partials_slot,
                             const float* __restrict__ u, const int* __restrict__ vptr,
                             const float* __restrict__ W6, const float* __restrict__ W7,
                             const float* __restrict__ w5, float* __restrict__ out)
{
    __shared__ float ps[2][DIM], ss[DIM], hred[128];
    const int tid = threadIdx.x;  // 128 threads
    const int d = tid & 63, sub = tid >> 6;
    float acc = 0.f;
    for (int p = sub; p < UPDBLK; p += 2) acc += partials_slot[p * DIM + d];
    ps[sub][d] = acc;
    __syncthreads();
    if (tid < 64) ss[tid] = ps[0][tid] + ps[1][tid];
    __syncthreads();
    const int v = *vptr;
    float h = 0.f;
    if (tid < 64) {
        #pragma unroll
        for (int k = 0; k < DIM; ++k) h += W6[tid * DIM + k] * ss[k];
    } else {
        const float* uv = u + (size_t)v * DIM;
        #pragma unroll
        for (int k = 0; k < DIM; ++k) h += W7[(tid - 64) * DIM + k] * uv[k];
    }
    hred[tid] = fmaxf(h, 0.f) * w5[tid];
    __syncthreads();
    if (tid == 0) {
        float s = 0.f;
        for (int i = 0; i < 128; ++i) s += hred[i];
        out[0] = s;
    }
}

extern "C" void kernel_launch(void* const* d_in, const int* in_sizes, int n_in,
                              void* d_out, int out_size, void* d_ws, size_t ws_size,
                              hipStream_t stream) {
    const float* graph  = (const float*)d_in[0];
    const int*   s_mask = (const int*)d_in[1];
    const int*   vptr   = (const int*)d_in[2];
    const float* w1     = (const float*)d_in[3];
    const float* W2     = (const float*)d_in[4];
    const float* W3     = (const float*)d_in[5];
    const float* w4     = (const float*)d_in[6];
    const float* w5     = (const float*)d_in[7];
    const float* W6     = (const float*)d_in[8];
    const float* W7     = (const float*)d_in[9];
    float* out = (float*)d_out;

    float* ws       = (float*)d_ws;
    float* pos      = ws;                      // NN
    float* neg      = pos + NN;                // NN
    float* u        = neg + NN;                // NN*DIM
    float* partials = u + (size_t)NN * DIM;    // 4 * SLOT floats (~2 MB)

    rowsum_init_kernel<<<RSBLK, 256, 0, stream>>>(graph, s_mask, W3, w4, w1,
                                                  pos, neg, u, partials);
    upd_kernel<<<UPDBLK, 256, 0, stream>>>(s_mask, w1, W2, W3, w4, pos, neg,
                                           u, partials, 0, RSBLK);
    upd_kernel<<<UPDBLK, 256, 0, stream>>>(s_mask, w1, W2, W3, w4, pos, neg,
                                           u, partials, 1, UPDBLK);
    upd_kernel<<<UPDBLK, 256, 0, stream>>>(s_mask, w1, W2, W3, w4, pos, neg,
                                           u, partials, 2, UPDBLK);
    final_kernel<<<1, 128, 0, stream>>>(partials + (size_t)3 * SLOT, u, vptr,
                                        W6, W7, w5, out);
}